// Round 9
// baseline (381.887 us; speedup 1.0000x reference)
//
#include <hip/hip_runtime.h>

// Fused FSAS, chunk=16 + AGPR-hoisted B-fragments + 2-barrier/chunk pipeline:
// hid double-buffer (h1/h2) and qs double-buffer let each chunk run as
//   P_a: B1q(c)->h1 [MFMA] || B2k(c-1): h2->ks [VALU]
//   P_b: B3(c-1) [VALU, fenced] || B1k(c)->h2 [MFMA] || B2q(c): h1->qs[c&1]
// (14 barriers in qk loop vs 24). All buffer writers >=1 sync after last
// reader; qs alternates so B3(c-1) reads the buffer B2q(c) doesn't write.
// AGPR frags ("=a" launder) keep arch VGPRs at 64, no spill (r8: WRITE=49MB).
// AV_STR 36 (was 40): epilogue store bank step {0,8,16,24} -> 8-way (was 16).
// LDS 38912 B -> 4 blocks/CU. XT_STR=52; xs_t pad cols 48..51 zeroed.

#define B_ 4
#define C_ 48
#define H_ 256
#define W_ 256
#define ROWS 68       // halo row width (66 valid)
#define XT_STR 52     // xs_t ushort stride; pad cols zeroed; spill reads finite
#define HID_STR 204   // hid ushort stride (3*68; p<204 stored)
#define QK_STR 68     // qs/ks fp32 stride
#define AV_STR 36     // av ushort stride (8B-aligned rows; cols 0..31 real)

// ---- LDS offsets (bytes); xs_t[208][52]=21632 aliases [0,21632) pre-hoist ----
#define OFF_H1  0        // ushort h1[16][204] = 6528 (alias: LN partials 2048)
#define OFF_H2  6528     // ushort h2[16][204] = 6528
#define OFF_QSA 13056    // float qsA[16][68] = 4352 (alias: avp ushort[64][36]=4608)
#define OFF_QSB 17408    // float qsB[16][68] = 4352
#define OFF_KS  21760    // float ks[16][68] = 4352
#define OFF_OSH 26112    // ushort osh[96][64] = 12288
#define OFF_MU  38400    // float[64]
#define OFF_RS  38656    // float[64]
#define SMEM_BYTES 38912 // 4 blocks/CU (<= 40960)

typedef __attribute__((ext_vector_type(8))) short short8;
typedef __attribute__((ext_vector_type(4))) float floatx4;
union U128 { unsigned long long u[2]; short8 s; };

__device__ __forceinline__ float bf2f(unsigned short u) {
  return __uint_as_float(((unsigned int)u) << 16);
}
__device__ __forceinline__ unsigned short f2bf(float f) {  // RNE
  unsigned int x = __float_as_uint(f);
  x += 0x7FFFu + ((x >> 16) & 1u);
  return (unsigned short)(x >> 16);
}
__device__ __forceinline__ unsigned long long pack4(float a, float b, float c, float d) {
  return (unsigned long long)f2bf(a) | ((unsigned long long)f2bf(b) << 16) |
         ((unsigned long long)f2bf(c) << 32) | ((unsigned long long)f2bf(d) << 48);
}

// ---- weight prep into d_ws (ushort units), all tiles dense ----
// wqk[6][32][64]: rows 0..15 = q (ch*16+m), 16..31 = k (96+ch*16+m-16); kk>=48 -> 0
// wv1[6][16][64]: rows = v (192+ch*16+m); kk>=48 -> 0            (at +12288)
// w2p[3][48][32]: [pr][co][kk] = wo[co*96 + pr*32 + kk]          (at +18432)
__global__ void fsas_prep(const float* __restrict__ wh, const float* __restrict__ wo,
                          unsigned short* __restrict__ ws) {
  int idx = blockIdx.x * 256 + threadIdx.x;
  if (idx < 12288) {
    int kk = idx & 63, t = idx >> 6;
    int m = t & 31, ch = t >> 5;
    float v = 0.f;
    if (kk < 48) {
      int c6 = (m < 16) ? (ch * 16 + m) : (96 + ch * 16 + (m - 16));
      v = wh[c6 * 48 + kk];
    }
    ws[idx] = f2bf(v);
  } else if (idx < 18432) {
    int e = idx - 12288;
    int kk = e & 63, t = e >> 6;
    int m = t & 15, ch = t >> 4;
    float v = (kk < 48) ? wh[(192 + ch * 16 + m) * 48 + kk] : 0.f;
    ws[idx] = f2bf(v);
  } else if (idx < 23040) {
    int e = idx - 18432;
    int kk = e & 31, t = e >> 5;
    int co = t % 48, pr = t / 48;
    ws[idx] = f2bf(wo[co * 96 + pr * 32 + kk]);
  }
}

__global__ __launch_bounds__(256, 4) void fsas_fused(
    const float* __restrict__ x,   const float* __restrict__ bh,
    const float* __restrict__ wdw, const float* __restrict__ bdw,
    const float* __restrict__ gam, const float* __restrict__ bet,
    const float* __restrict__ bo,  const unsigned short* __restrict__ ws,
    float* __restrict__ y)
{
  __shared__ __align__(16) char smem[SMEM_BYTES];
  unsigned short* xs_t = (unsigned short*)(smem);          // pre-hoist alias
  unsigned short* h1  = (unsigned short*)(smem + OFF_H1);
  unsigned short* h2  = (unsigned short*)(smem + OFF_H2);
  float* qsA = (float*)(smem + OFF_QSA);
  float* qsB = (float*)(smem + OFF_QSB);
  float* ks  = (float*)(smem + OFF_KS);
  unsigned short* osh = (unsigned short*)(smem + OFF_OSH);
  float* mu = (float*)(smem + OFF_MU);
  float* rs = (float*)(smem + OFF_RS);
  unsigned short* avp = (unsigned short*)(smem + OFF_QSA); // alias (v loop)
  float2* part = (float2*)(smem + OFF_H1);                 // alias (LN)

  const unsigned short* wqk = ws;
  const unsigned short* wv1 = ws + 12288;
  const unsigned short* w2p = ws + 18432;

  const int tid  = threadIdx.x;
  const int wseg = blockIdx.x;
  const int h    = blockIdx.y;
  const int b    = blockIdx.z;
  const int w0   = wseg * 64;
  const int lane = tid & 63;
  const int wv   = tid >> 6;
  const int ln   = lane & 15;
  const int quad = lane >> 4;
  const int pbase = wv * 16 + ln;   // nt-tile i covers p = pbase + 64*i

  // ---- Stage A: x halo -> xs_t[p][c] bf16, coalesced along w ----
  // Pad cols 48..51 of every row zeroed (MFMA reads them; 0*NaN=NaN).
  for (int p = tid; p < 208; p += 256)
    *(unsigned long long*)(xs_t + p * XT_STR + 48) = 0ull;
  if (tid < 8) *(unsigned int*)(smem + 21632 + tid * 4) = 0u;  // spill guard (32B)
  for (int r = wv; r < 144; r += 4) {
    int c = r / 3, rr = r - c * 3;
    int gr = h - 1 + rr;
    bool rok = (gr >= 0) && (gr < H_);
    const float* xrow = x + (((b * C_) + c) * H_ + (rok ? gr : 0)) * W_;
    {
      int cc = lane, gc = w0 - 1 + cc;
      float v = 0.f;
      if (rok && gc >= 0 && gc < W_) v = xrow[gc];
      xs_t[(rr * ROWS + cc) * XT_STR + c] = f2bf(v);
    }
    if (lane < 4) {
      int cc = 64 + lane, gc = w0 - 1 + cc;
      float v = 0.f;
      if (cc < 66 && rok && gc < W_) v = xrow[gc];
      xs_t[(rr * ROWS + cc) * XT_STR + c] = f2bf(v);
    }
  }
  __syncthreads();

  // ---- Fragment hoist into AGPRs: load to VGPR, launder via "=a" asm ----
  short8 f00, f01, f10, f11, f20, f21, f30, f31;
  int pvm = 0;
  {
    U128 t0, t1;
    const unsigned short* bp0 = xs_t + (pbase)       * XT_STR + quad * 8;
    const unsigned short* bp1 = xs_t + (pbase + 64)  * XT_STR + quad * 8;
    const unsigned short* bp2 = xs_t + (pbase + 128) * XT_STR + quad * 8;
    t0.u[0] = *(const unsigned long long*)(bp0);
    t0.u[1] = *(const unsigned long long*)(bp0 + 4);
    t1.u[0] = *(const unsigned long long*)(bp0 + 32);
    t1.u[1] = *(const unsigned long long*)(bp0 + 36);
    asm("" : "=a"(f00) : "0"(t0.s));
    asm("" : "=a"(f01) : "0"(t1.s));
    t0.u[0] = *(const unsigned long long*)(bp1);
    t0.u[1] = *(const unsigned long long*)(bp1 + 4);
    t1.u[0] = *(const unsigned long long*)(bp1 + 32);
    t1.u[1] = *(const unsigned long long*)(bp1 + 36);
    asm("" : "=a"(f10) : "0"(t0.s));
    asm("" : "=a"(f11) : "0"(t1.s));
    t0.u[0] = *(const unsigned long long*)(bp2);
    t0.u[1] = *(const unsigned long long*)(bp2 + 4);
    t1.u[0] = *(const unsigned long long*)(bp2 + 32);
    t1.u[1] = *(const unsigned long long*)(bp2 + 36);
    asm("" : "=a"(f20) : "0"(t0.s));
    asm("" : "=a"(f21) : "0"(t1.s));
    t0.u[0] = 0ull; t0.u[1] = 0ull; t1.u[0] = 0ull; t1.u[1] = 0ull;
    if (wv == 0) {
      const unsigned short* bp3 = xs_t + (pbase + 192) * XT_STR + quad * 8;
      t0.u[0] = *(const unsigned long long*)(bp3);
      t0.u[1] = *(const unsigned long long*)(bp3 + 4);
      t1.u[0] = *(const unsigned long long*)(bp3 + 32);
      t1.u[1] = *(const unsigned long long*)(bp3 + 36);
    }
    asm("" : "=a"(f30) : "0"(t0.s));
    asm("" : "=a"(f31) : "0"(t1.s));
    #pragma unroll
    for (int i = 0; i < 4; ++i) {
      int p = pbase + i * 64;
      int rr = p / ROWS, cc = p - rr * ROWS;
      int gr = h - 1 + rr, gc = w0 - 1 + cc;
      bool pv = (rr < 3) && (cc < 66) && (gr >= 0) && (gr < H_) && (gc >= 0) && (gc < W_);
      pvm |= (pv ? 1 : 0) << i;
    }
  }
  __syncthreads();   // xs_t dead; all LDS buffers may now be written

  // ---- helpers ----
  // B1: M=16 (dense) x N=208 x K=48(pad 64) MFMA from AGPR frags -> hb (hid buf)
  auto run_b1 = [&](const unsigned short* wA, int arow, int bhb, unsigned short* hbuf) {
    short8 a0 = *(const short8*)(wA + ((arow + ln) * 64 + quad * 8));
    short8 a1 = *(const short8*)(wA + ((arow + ln) * 64 + 32 + quad * 8));
    floatx4 bb;
    #pragma unroll
    for (int r = 0; r < 4; ++r) bb[r] = bh[bhb + quad * 4 + r];
    unsigned short* hb = hbuf + (quad * 4) * HID_STR + pbase;
    {
      floatx4 acc = bb;
      acc = __builtin_amdgcn_mfma_f32_16x16x32_bf16(a0, f00, acc, 0, 0, 0);
      acc = __builtin_amdgcn_mfma_f32_16x16x32_bf16(a1, f01, acc, 0, 0, 0);
      bool pv = (pvm & 1) != 0;
      #pragma unroll
      for (int r = 0; r < 4; ++r) hb[r * HID_STR] = pv ? f2bf(acc[r]) : (unsigned short)0;
    }
    {
      floatx4 acc = bb;
      acc = __builtin_amdgcn_mfma_f32_16x16x32_bf16(a0, f10, acc, 0, 0, 0);
      acc = __builtin_amdgcn_mfma_f32_16x16x32_bf16(a1, f11, acc, 0, 0, 0);
      bool pv = (pvm & 2) != 0;
      #pragma unroll
      for (int r = 0; r < 4; ++r) hb[r * HID_STR + 64] = pv ? f2bf(acc[r]) : (unsigned short)0;
    }
    {
      floatx4 acc = bb;
      acc = __builtin_amdgcn_mfma_f32_16x16x32_bf16(a0, f20, acc, 0, 0, 0);
      acc = __builtin_amdgcn_mfma_f32_16x16x32_bf16(a1, f21, acc, 0, 0, 0);
      bool pv = (pvm & 4) != 0;
      #pragma unroll
      for (int r = 0; r < 4; ++r) hb[r * HID_STR + 128] = pv ? f2bf(acc[r]) : (unsigned short)0;
    }
    if (wv == 0) {   // nt=12: p = ln+192; store iff p<204 (ln<12)
      floatx4 acc = bb;
      acc = __builtin_amdgcn_mfma_f32_16x16x32_bf16(a0, f30, acc, 0, 0, 0);
      acc = __builtin_amdgcn_mfma_f32_16x16x32_bf16(a1, f31, acc, 0, 0, 0);
      bool pv = (pvm & 8) != 0;
      if (ln < 12) {
        #pragma unroll
        for (int r = 0; r < 4; ++r) hb[r * HID_STR + 192] = pv ? f2bf(acc[r]) : (unsigned short)0;
      }
    }
  };
  // B2: depthwise 3x3 on hsrc rows 0..15 -> dst fp32 (256 units: 16ch x 4px)
  auto run_b2 = [&](int c6base, float* dst, const unsigned short* hsrc) {
    int cl = tid >> 4, pg4 = tid & 15, p0 = pg4 * 4;
    int c6 = c6base + cl;
    const float* wd = wdw + c6 * 9;
    float bb = bdw[c6];
    float a4[4] = {bb, bb, bb, bb};
    #pragma unroll
    for (int di = 0; di < 3; ++di) {
      const unsigned short* hrow = hsrc + cl * HID_STR + di * ROWS + p0;
      unsigned long long lo = *(const unsigned long long*)(hrow);
      unsigned int ex = *(const unsigned int*)(hrow + 4);
      float hf[6];
      #pragma unroll
      for (int t = 0; t < 4; ++t) hf[t] = bf2f((unsigned short)(lo >> (16 * t)));
      hf[4] = bf2f((unsigned short)ex);
      hf[5] = bf2f((unsigned short)(ex >> 16));
      #pragma unroll
      for (int dj = 0; dj < 3; ++dj) {
        float w = wd[di * 3 + dj];
        #pragma unroll
        for (int t = 0; t < 4; ++t) a4[t] += w * hf[t + dj];
      }
    }
    *(float4*)(dst + cl * QK_STR + p0) = make_float4(a4[0], a4[1], a4[2], a4[3]);
  };
  // B3: 8x8 circular conv, fp32 (256 units: 16ch x uu x vhalf) -> osh
  auto run_b3 = [&](int c2base, const float* qsrc) {
    int cl = tid >> 4, r4 = tid & 15, uu = r4 >> 1, vh = r4 & 1;
    const float* qrow = qsrc + cl * QK_STR;
    const float* krow = ks + cl * QK_STR;
    float a4[4] = {0.f, 0.f, 0.f, 0.f};
    #pragma unroll
    for (int i = 0; i < 8; ++i) {
      float4 q0 = *(const float4*)(qrow + i * 8);
      float4 q1 = *(const float4*)(qrow + i * 8 + 4);
      int ri = (uu - i) & 7;
      float4 ka = *(const float4*)(krow + ri * 8 + vh * 4);
      float4 kb = *(const float4*)(krow + ri * 8 + (vh ^ 1) * 4);
      float qf[8] = {q0.x, q0.y, q0.z, q0.w, q1.x, q1.y, q1.z, q1.w};
      float kr[8] = {ka.x, ka.y, ka.z, ka.w, kb.x, kb.y, kb.z, kb.w};
      #pragma unroll
      for (int vvi = 0; vvi < 4; ++vvi)
        #pragma unroll
        for (int j = 0; j < 8; ++j)
          a4[vvi] += qf[j] * kr[(vvi - j) & 7];
    }
    int c2 = c2base + cl;
    *(unsigned long long*)(osh + c2 * 64 + uu * 8 + vh * 4) = pack4(a4[0], a4[1], a4[2], a4[3]);
  };

  // ======== qk chunk loop: 2-barrier pipeline (h1/h2 + qsA/qsB dbuf) ========
  #pragma unroll 1
  for (int chunk = 0; chunk < 6; ++chunk) {
    // P_a: B1q(c)->h1 [MFMA] || B2k(c-1): h2->ks [VALU]
    run_b1(wqk, chunk * 32, chunk * 16, h1);
    if (chunk > 0) run_b2(96 + (chunk - 1) * 16, ks, h2);
    __syncthreads();
    // P_b: B3(c-1) [VALU, fenced] || B1k(c)->h2 [MFMA] || B2q(c): h1->qs[c&1]
    if (chunk > 0) run_b3((chunk - 1) * 16, (chunk & 1) ? qsA : qsB);
    __builtin_amdgcn_sched_barrier(0);
    run_b1(wqk, chunk * 32 + 16, 96 + chunk * 16, h2);
    run_b2(chunk * 16, (chunk & 1) ? qsB : qsA, h1);
    __syncthreads();
  }
  // tail: B2k(5) then B3(5)
  run_b2(96 + 80, ks, h2);
  __syncthreads();
  run_b3(80, qsB);   // chunk 5: qs[5&1] = qsB
  __syncthreads();

  // ======== LayerNorm stats (parallel: 4 channel-segments x 64 px) ========
  {
    int p = tid & 63, seg = tid >> 6;
    float s = 0.f, s2 = 0.f;
    for (int c = seg * 24; c < seg * 24 + 24; ++c) {
      float ov = bf2f(osh[c * 64 + p]);
      s += ov; s2 += ov * ov;
    }
    part[seg * 64 + p] = make_float2(s, s2);
  }
  __syncthreads();
  if (tid < 64) {
    float s = 0.f, s2 = 0.f;
    #pragma unroll
    for (int seg = 0; seg < 4; ++seg) {
      float2 pr2 = part[seg * 64 + tid];
      s += pr2.x; s2 += pr2.y;
    }
    float m = s * (1.f / 96.f);
    float var = s2 * (1.f / 96.f) - m * m;
    mu[tid] = m;
    rs[tid] = rsqrtf(var + 1e-5f);
  }
  __syncthreads();

  // ======== v loop: deferred v-branch + dense K=32 final conv accumulate ====
  floatx4 oacc[3];
  #pragma unroll
  for (int mt = 0; mt < 3; ++mt)
    #pragma unroll
    for (int r = 0; r < 4; ++r) oacc[mt][r] = bo[mt * 16 + quad * 4 + r];

  #pragma unroll 1
  for (int pr = 0; pr < 3; ++pr) {
    #pragma unroll 1
    for (int sub = 0; sub < 2; ++sub) {
      int chunk = pr * 2 + sub;
      run_b1(wv1, chunk * 16, 192 + chunk * 16, h1);
      __syncthreads();
      // B2v + epilogue: 256 units (16 ch x 16 quad-px groups), 4 px each
      {
        int lc = tid >> 4, pg4 = tid & 15, p0 = pg4 * 4;
        int c2 = chunk * 16 + lc, c6 = 192 + c2;
        const float* wd = wdw + c6 * 9;
        float bb = bdw[c6];
        float a4[4] = {bb, bb, bb, bb};
        #pragma unroll
        for (int di = 0; di < 3; ++di) {
          const unsigned short* hrow = h1 + lc * HID_STR + di * ROWS + p0;
          unsigned long long lo = *(const unsigned long long*)(hrow);
          unsigned int ex = *(const unsigned int*)(hrow + 4);
          float hf[6];
          #pragma unroll
          for (int t = 0; t < 4; ++t) hf[t] = bf2f((unsigned short)(lo >> (16 * t)));
          hf[4] = bf2f((unsigned short)ex);
          hf[5] = bf2f((unsigned short)(ex >> 16));
          #pragma unroll
          for (int dj = 0; dj < 3; ++dj) {
            float w = wd[di * 3 + dj];
            #pragma unroll
            for (int t = 0; t < 4; ++t) a4[t] += w * hf[t + dj];
          }
        }
        float gv = gam[c2], bev = bet[c2];
        #pragma unroll
        for (int t = 0; t < 4; ++t) {
          int p = p0 + t;
          float o = bf2f(osh[c2 * 64 + p]);
          float a = ((o - mu[p]) * rs[p] * gv + bev) * a4[t];
          avp[p * AV_STR + sub * 16 + lc] = f2bf(a);
        }
      }
      __syncthreads();
    }
    // final-conv K-split MFMA: K rows 0..31 = c2 32*pr..+31, fully dense.
    __builtin_amdgcn_sched_barrier(0);
    {
      const unsigned short* bp = avp + (wv * 16 + ln) * AV_STR + quad * 8;
      U128 bfr;
      bfr.u[0] = *(const unsigned long long*)(bp);
      bfr.u[1] = *(const unsigned long long*)(bp + 4);
      #pragma unroll
      for (int mt = 0; mt < 3; ++mt) {
        short8 af = *(const short8*)(w2p + ((pr * 48 + mt * 16 + ln) * 32 + quad * 8));
        oacc[mt] = __builtin_amdgcn_mfma_f32_16x16x32_bf16(af, bfr.s, oacc[mt], 0, 0, 0);
      }
    }
  }

  // ---- store y ----
  #pragma unroll
  for (int mt = 0; mt < 3; ++mt)
    #pragma unroll
    for (int r = 0; r < 4; ++r) {
      int co = mt * 16 + quad * 4 + r;
      y[(((b * C_) + co) * H_ + h) * W_ + w0 + wv * 16 + ln] = oacc[mt][r];
    }
}

extern "C" void kernel_launch(void* const* d_in, const int* in_sizes, int n_in,
                              void* d_out, int out_size, void* d_ws, size_t ws_size,
                              hipStream_t stream) {
  const float* x   = (const float*)d_in[0];
  const float* wh  = (const float*)d_in[1];
  const float* bh  = (const float*)d_in[2];
  const float* wdw = (const float*)d_in[3];
  const float* bdw = (const float*)d_in[4];
  const float* g   = (const float*)d_in[5];
  const float* be  = (const float*)d_in[6];
  const float* wo  = (const float*)d_in[7];
  const float* bo  = (const float*)d_in[8];
  float* y = (float*)d_out;
  unsigned short* ws = (unsigned short*)d_ws;   // 23040 ushorts

  fsas_prep<<<dim3(90), 256, 0, stream>>>(wh, wo, ws);
  dim3 grid(4, H_, B_);
  fsas_fused<<<grid, 256, 0, stream>>>(x, bh, wdw, bdw, g, be, bo, ws, y);
}

// Round 11
// 374.126 us; speedup vs baseline: 1.0207x; 1.0207x over previous
//
#include <hip/hip_runtime.h>

// Fused FSAS, chunk=16, q/k split passes + AGPR-hoisted MFMA B-fragments.
// = round-8 kernel (proven: no spill, WRITE=49MB, ~313us) + AV_STR 36
// (r9-proven conflict fix: epilogue store bank step {0,8,16,24} -> 8-way).
// r10's fp32-hid variant failed nondeterministically -> reverted; bf16 hid.
// Frags laundered to AGPRs ("=a" asm): arch VGPRs stay 64, acc in AGPRs,
// unified-file budget respected. sched_barrier(0) fences keep B3/B1 register
// pressure = max not sum; unroll 1 on chunk/pr/sub loops.
// B operand (input tile) identical across all 18 B1 calls -> loaded once;
// xs_t LDS dead after hoist, aliases hid/qs/ks/osh -> LDS 28032 B.
// conv1x1(48->288 MFMA) -> dw3x3 -> 8x8 circ conv -> LayerNorm(96) ->
// v*normed -> conv1x1(96->48, dense K=32 split MFMA).
// XT_STR=52; xs_t pad cols 48..51 zeroed (0*NaN=NaN in MFMA).

#define B_ 4
#define C_ 48
#define H_ 256
#define W_ 256
#define ROWS 68       // halo row width (66 valid)
#define XT_STR 52     // xs_t ushort stride; pad cols zeroed; spill reads finite
#define HID_STR 204   // hid ushort stride (3*68; p<204 stored)
#define QK_STR 68     // qs/ks fp32 stride
#define AV_STR 36     // av ushort stride (8B-aligned rows; cols 0..31 real)

// ---- LDS offsets (bytes); xs_t[208][52]=21632 aliases [0,21632) pre-hoist ----
#define OFF_HID 0        // ushort hid[16][204] = 6528 (alias: LN partials 2048)
#define OFF_QS  6528     // float qs[16][68] = 4352 (alias: avp ushort[64][36]=4608 spans into dead ks)
#define OFF_KS  10880    // float ks[16][68] = 4352
#define OFF_OSH 15232    // ushort osh[96][64] = 12288
#define OFF_MU  27520    // float[64]
#define OFF_RS  27776    // float[64]
#define SMEM_BYTES 28032

typedef __attribute__((ext_vector_type(8))) short short8;
typedef __attribute__((ext_vector_type(4))) float floatx4;
union U128 { unsigned long long u[2]; short8 s; };

__device__ __forceinline__ float bf2f(unsigned short u) {
  return __uint_as_float(((unsigned int)u) << 16);
}
__device__ __forceinline__ unsigned short f2bf(float f) {  // RNE
  unsigned int x = __float_as_uint(f);
  x += 0x7FFFu + ((x >> 16) & 1u);
  return (unsigned short)(x >> 16);
}
__device__ __forceinline__ unsigned long long pack4(float a, float b, float c, float d) {
  return (unsigned long long)f2bf(a) | ((unsigned long long)f2bf(b) << 16) |
         ((unsigned long long)f2bf(c) << 32) | ((unsigned long long)f2bf(d) << 48);
}

// ---- weight prep into d_ws (ushort units), all tiles dense ----
// wqk[6][32][64]: rows 0..15 = q (ch*16+m), 16..31 = k (96+ch*16+m-16); kk>=48 -> 0
// wv1[6][16][64]: rows = v (192+ch*16+m); kk>=48 -> 0            (at +12288)
// w2p[3][48][32]: [pr][co][kk] = wo[co*96 + pr*32 + kk]          (at +18432)
__global__ void fsas_prep(const float* __restrict__ wh, const float* __restrict__ wo,
                          unsigned short* __restrict__ ws) {
  int idx = blockIdx.x * 256 + threadIdx.x;
  if (idx < 12288) {
    int kk = idx & 63, t = idx >> 6;
    int m = t & 31, ch = t >> 5;
    float v = 0.f;
    if (kk < 48) {
      int c6 = (m < 16) ? (ch * 16 + m) : (96 + ch * 16 + (m - 16));
      v = wh[c6 * 48 + kk];
    }
    ws[idx] = f2bf(v);
  } else if (idx < 18432) {
    int e = idx - 12288;
    int kk = e & 63, t = e >> 6;
    int m = t & 15, ch = t >> 4;
    float v = (kk < 48) ? wh[(192 + ch * 16 + m) * 48 + kk] : 0.f;
    ws[idx] = f2bf(v);
  } else if (idx < 23040) {
    int e = idx - 18432;
    int kk = e & 31, t = e >> 5;
    int co = t % 48, pr = t / 48;
    ws[idx] = f2bf(wo[co * 96 + pr * 32 + kk]);
  }
}

__global__ __launch_bounds__(256, 4) void fsas_fused(
    const float* __restrict__ x,   const float* __restrict__ bh,
    const float* __restrict__ wdw, const float* __restrict__ bdw,
    const float* __restrict__ gam, const float* __restrict__ bet,
    const float* __restrict__ bo,  const unsigned short* __restrict__ ws,
    float* __restrict__ y)
{
  __shared__ __align__(16) char smem[SMEM_BYTES];
  unsigned short* xs_t = (unsigned short*)(smem);          // pre-hoist alias
  unsigned short* hid  = (unsigned short*)(smem + OFF_HID);
  float* qs = (float*)(smem + OFF_QS);
  float* ks = (float*)(smem + OFF_KS);
  unsigned short* osh = (unsigned short*)(smem + OFF_OSH);
  float* mu = (float*)(smem + OFF_MU);
  float* rs = (float*)(smem + OFF_RS);
  unsigned short* avp = (unsigned short*)(smem + OFF_QS);  // alias (v loop)
  float2* part = (float2*)(smem + OFF_HID);                // alias (LN)

  const unsigned short* wqk = ws;
  const unsigned short* wv1 = ws + 12288;
  const unsigned short* w2p = ws + 18432;

  const int tid  = threadIdx.x;
  const int wseg = blockIdx.x;
  const int h    = blockIdx.y;
  const int b    = blockIdx.z;
  const int w0   = wseg * 64;
  const int lane = tid & 63;
  const int wv   = tid >> 6;
  const int ln   = lane & 15;
  const int quad = lane >> 4;
  const int pbase = wv * 16 + ln;   // nt-tile i covers p = pbase + 64*i

  // ---- Stage A: x halo -> xs_t[p][c] bf16, coalesced along w ----
  // Pad cols 48..51 of every row zeroed (MFMA reads them; 0*NaN=NaN).
  for (int p = tid; p < 208; p += 256)
    *(unsigned long long*)(xs_t + p * XT_STR + 48) = 0ull;
  if (tid < 8) *(unsigned int*)(smem + 21632 + tid * 4) = 0u;  // spill guard (32B)
  for (int r = wv; r < 144; r += 4) {
    int c = r / 3, rr = r - c * 3;
    int gr = h - 1 + rr;
    bool rok = (gr >= 0) && (gr < H_);
    const float* xrow = x + (((b * C_) + c) * H_ + (rok ? gr : 0)) * W_;
    {
      int cc = lane, gc = w0 - 1 + cc;
      float v = 0.f;
      if (rok && gc >= 0 && gc < W_) v = xrow[gc];
      xs_t[(rr * ROWS + cc) * XT_STR + c] = f2bf(v);
    }
    if (lane < 4) {
      int cc = 64 + lane, gc = w0 - 1 + cc;
      float v = 0.f;
      if (cc < 66 && rok && gc < W_) v = xrow[gc];
      xs_t[(rr * ROWS + cc) * XT_STR + c] = f2bf(v);
    }
  }
  __syncthreads();

  // ---- Fragment hoist into AGPRs: load to VGPR, launder via "=a" asm ----
  short8 f00, f01, f10, f11, f20, f21, f30, f31;
  int pvm = 0;
  {
    U128 t0, t1;
    const unsigned short* bp0 = xs_t + (pbase)       * XT_STR + quad * 8;
    const unsigned short* bp1 = xs_t + (pbase + 64)  * XT_STR + quad * 8;
    const unsigned short* bp2 = xs_t + (pbase + 128) * XT_STR + quad * 8;
    t0.u[0] = *(const unsigned long long*)(bp0);
    t0.u[1] = *(const unsigned long long*)(bp0 + 4);
    t1.u[0] = *(const unsigned long long*)(bp0 + 32);
    t1.u[1] = *(const unsigned long long*)(bp0 + 36);
    asm("" : "=a"(f00) : "0"(t0.s));
    asm("" : "=a"(f01) : "0"(t1.s));
    t0.u[0] = *(const unsigned long long*)(bp1);
    t0.u[1] = *(const unsigned long long*)(bp1 + 4);
    t1.u[0] = *(const unsigned long long*)(bp1 + 32);
    t1.u[1] = *(const unsigned long long*)(bp1 + 36);
    asm("" : "=a"(f10) : "0"(t0.s));
    asm("" : "=a"(f11) : "0"(t1.s));
    t0.u[0] = *(const unsigned long long*)(bp2);
    t0.u[1] = *(const unsigned long long*)(bp2 + 4);
    t1.u[0] = *(const unsigned long long*)(bp2 + 32);
    t1.u[1] = *(const unsigned long long*)(bp2 + 36);
    asm("" : "=a"(f20) : "0"(t0.s));
    asm("" : "=a"(f21) : "0"(t1.s));
    t0.u[0] = 0ull; t0.u[1] = 0ull; t1.u[0] = 0ull; t1.u[1] = 0ull;
    if (wv == 0) {
      const unsigned short* bp3 = xs_t + (pbase + 192) * XT_STR + quad * 8;
      t0.u[0] = *(const unsigned long long*)(bp3);
      t0.u[1] = *(const unsigned long long*)(bp3 + 4);
      t1.u[0] = *(const unsigned long long*)(bp3 + 32);
      t1.u[1] = *(const unsigned long long*)(bp3 + 36);
    }
    asm("" : "=a"(f30) : "0"(t0.s));
    asm("" : "=a"(f31) : "0"(t1.s));
    #pragma unroll
    for (int i = 0; i < 4; ++i) {
      int p = pbase + i * 64;
      int rr = p / ROWS, cc = p - rr * ROWS;
      int gr = h - 1 + rr, gc = w0 - 1 + cc;
      bool pv = (rr < 3) && (cc < 66) && (gr >= 0) && (gr < H_) && (gc >= 0) && (gc < W_);
      pvm |= (pv ? 1 : 0) << i;
    }
  }
  __syncthreads();   // xs_t dead; hid/qs/ks/osh may now be written

  // ---- helpers ----
  // B1: M=16 (dense) x N=208 x K=48(pad 64) MFMA from AGPR frags -> hid
  auto run_b1 = [&](const unsigned short* wA, int arow, int bhb) {
    short8 a0 = *(const short8*)(wA + ((arow + ln) * 64 + quad * 8));
    short8 a1 = *(const short8*)(wA + ((arow + ln) * 64 + 32 + quad * 8));
    floatx4 bb;
    #pragma unroll
    for (int r = 0; r < 4; ++r) bb[r] = bh[bhb + quad * 4 + r];
    unsigned short* hb = hid + (quad * 4) * HID_STR + pbase;
    {
      floatx4 acc = bb;
      acc = __builtin_amdgcn_mfma_f32_16x16x32_bf16(a0, f00, acc, 0, 0, 0);
      acc = __builtin_amdgcn_mfma_f32_16x16x32_bf16(a1, f01, acc, 0, 0, 0);
      bool pv = (pvm & 1) != 0;
      #pragma unroll
      for (int r = 0; r < 4; ++r) hb[r * HID_STR] = pv ? f2bf(acc[r]) : (unsigned short)0;
    }
    {
      floatx4 acc = bb;
      acc = __builtin_amdgcn_mfma_f32_16x16x32_bf16(a0, f10, acc, 0, 0, 0);
      acc = __builtin_amdgcn_mfma_f32_16x16x32_bf16(a1, f11, acc, 0, 0, 0);
      bool pv = (pvm & 2) != 0;
      #pragma unroll
      for (int r = 0; r < 4; ++r) hb[r * HID_STR + 64] = pv ? f2bf(acc[r]) : (unsigned short)0;
    }
    {
      floatx4 acc = bb;
      acc = __builtin_amdgcn_mfma_f32_16x16x32_bf16(a0, f20, acc, 0, 0, 0);
      acc = __builtin_amdgcn_mfma_f32_16x16x32_bf16(a1, f21, acc, 0, 0, 0);
      bool pv = (pvm & 4) != 0;
      #pragma unroll
      for (int r = 0; r < 4; ++r) hb[r * HID_STR + 128] = pv ? f2bf(acc[r]) : (unsigned short)0;
    }
    if (wv == 0) {   // nt=12: p = ln+192; store iff p<204 (ln<12)
      floatx4 acc = bb;
      acc = __builtin_amdgcn_mfma_f32_16x16x32_bf16(a0, f30, acc, 0, 0, 0);
      acc = __builtin_amdgcn_mfma_f32_16x16x32_bf16(a1, f31, acc, 0, 0, 0);
      bool pv = (pvm & 8) != 0;
      if (ln < 12) {
        #pragma unroll
        for (int r = 0; r < 4; ++r) hb[r * HID_STR + 192] = pv ? f2bf(acc[r]) : (unsigned short)0;
      }
    }
  };
  // B2: depthwise 3x3 on hid rows 0..15 -> dst fp32 (256 units: 16ch x 4px)
  auto run_b2 = [&](int c6base, float* dst) {
    int cl = tid >> 4, pg4 = tid & 15, p0 = pg4 * 4;
    int c6 = c6base + cl;
    const float* wd = wdw + c6 * 9;
    float bb = bdw[c6];
    float a4[4] = {bb, bb, bb, bb};
    #pragma unroll
    for (int di = 0; di < 3; ++di) {
      const unsigned short* hrow = hid + cl * HID_STR + di * ROWS + p0;
      unsigned long long lo = *(const unsigned long long*)(hrow);
      unsigned int ex = *(const unsigned int*)(hrow + 4);
      float hf[6];
      #pragma unroll
      for (int t = 0; t < 4; ++t) hf[t] = bf2f((unsigned short)(lo >> (16 * t)));
      hf[4] = bf2f((unsigned short)ex);
      hf[5] = bf2f((unsigned short)(ex >> 16));
      #pragma unroll
      for (int dj = 0; dj < 3; ++dj) {
        float w = wd[di * 3 + dj];
        #pragma unroll
        for (int t = 0; t < 4; ++t) a4[t] += w * hf[t + dj];
      }
    }
    *(float4*)(dst + cl * QK_STR + p0) = make_float4(a4[0], a4[1], a4[2], a4[3]);
  };
  // B3: 8x8 circular conv, fp32 (256 units: 16ch x uu x vhalf) -> osh
  auto run_b3 = [&](int c2base) {
    int cl = tid >> 4, r4 = tid & 15, uu = r4 >> 1, vh = r4 & 1;
    const float* qrow = qs + cl * QK_STR;
    const float* krow = ks + cl * QK_STR;
    float a4[4] = {0.f, 0.f, 0.f, 0.f};
    #pragma unroll
    for (int i = 0; i < 8; ++i) {
      float4 q0 = *(const float4*)(qrow + i * 8);
      float4 q1 = *(const float4*)(qrow + i * 8 + 4);
      int ri = (uu - i) & 7;
      float4 ka = *(const float4*)(krow + ri * 8 + vh * 4);
      float4 kb = *(const float4*)(krow + ri * 8 + (vh ^ 1) * 4);
      float qf[8] = {q0.x, q0.y, q0.z, q0.w, q1.x, q1.y, q1.z, q1.w};
      float kr[8] = {ka.x, ka.y, ka.z, ka.w, kb.x, kb.y, kb.z, kb.w};
      #pragma unroll
      for (int vvi = 0; vvi < 4; ++vvi)
        #pragma unroll
        for (int j = 0; j < 8; ++j)
          a4[vvi] += qf[j] * kr[(vvi - j) & 7];
    }
    int c2 = c2base + cl;
    *(unsigned long long*)(osh + c2 * 64 + uu * 8 + vh * 4) = pack4(a4[0], a4[1], a4[2], a4[3]);
  };

  // ======== chunk loop: 6 chunks of 16 c2-channels, q/k passes split ========
  #pragma unroll 1
  for (int chunk = 0; chunk < 6; ++chunk) {
    // P1: B3(chunk-1) [VALU] then B1q(chunk) [MFMA] — fenced (pressure = max)
    if (chunk > 0) run_b3((chunk - 1) * 16);
    __builtin_amdgcn_sched_barrier(0);
    run_b1(wqk, chunk * 32, chunk * 16);
    __syncthreads();
    run_b2(chunk * 16, qs);
    __syncthreads();
    run_b1(wqk, chunk * 32 + 16, 96 + chunk * 16);
    __syncthreads();
    run_b2(96 + chunk * 16, ks);
    __syncthreads();
  }
  run_b3(80);
  __syncthreads();

  // ======== LayerNorm stats (parallel: 4 channel-segments x 64 px) ========
  {
    int p = tid & 63, seg = tid >> 6;
    float s = 0.f, s2 = 0.f;
    for (int c = seg * 24; c < seg * 24 + 24; ++c) {
      float ov = bf2f(osh[c * 64 + p]);
      s += ov; s2 += ov * ov;
    }
    part[seg * 64 + p] = make_float2(s, s2);
  }
  __syncthreads();
  if (tid < 64) {
    float s = 0.f, s2 = 0.f;
    #pragma unroll
    for (int seg = 0; seg < 4; ++seg) {
      float2 pr2 = part[seg * 64 + tid];
      s += pr2.x; s2 += pr2.y;
    }
    float m = s * (1.f / 96.f);
    float var = s2 * (1.f / 96.f) - m * m;
    mu[tid] = m;
    rs[tid] = rsqrtf(var + 1e-5f);
  }
  __syncthreads();

  // ======== v loop: deferred v-branch + dense K=32 final conv accumulate ====
  floatx4 oacc[3];
  #pragma unroll
  for (int mt = 0; mt < 3; ++mt)
    #pragma unroll
    for (int r = 0; r < 4; ++r) oacc[mt][r] = bo[mt * 16 + quad * 4 + r];

  #pragma unroll 1
  for (int pr = 0; pr < 3; ++pr) {
    #pragma unroll 1
    for (int sub = 0; sub < 2; ++sub) {
      int chunk = pr * 2 + sub;
      run_b1(wv1, chunk * 16, 192 + chunk * 16);
      __syncthreads();
      // B2v + epilogue: 256 units (16 ch x 16 quad-px groups), 4 px each
      {
        int lc = tid >> 4, pg4 = tid & 15, p0 = pg4 * 4;
        int c2 = chunk * 16 + lc, c6 = 192 + c2;
        const float* wd = wdw + c6 * 9;
        float bb = bdw[c6];
        float a4[4] = {bb, bb, bb, bb};
        #pragma unroll
        for (int di = 0; di < 3; ++di) {
          const unsigned short* hrow = hid + lc * HID_STR + di * ROWS + p0;
          unsigned long long lo = *(const unsigned long long*)(hrow);
          unsigned int ex = *(const unsigned int*)(hrow + 4);
          float hf[6];
          #pragma unroll
          for (int t = 0; t < 4; ++t) hf[t] = bf2f((unsigned short)(lo >> (16 * t)));
          hf[4] = bf2f((unsigned short)ex);
          hf[5] = bf2f((unsigned short)(ex >> 16));
          #pragma unroll
          for (int dj = 0; dj < 3; ++dj) {
            float w = wd[di * 3 + dj];
            #pragma unroll
            for (int t = 0; t < 4; ++t) a4[t] += w * hf[t + dj];
          }
        }
        float gv = gam[c2], bev = bet[c2];
        #pragma unroll
        for (int t = 0; t < 4; ++t) {
          int p = p0 + t;
          float o = bf2f(osh[c2 * 64 + p]);
          float a = ((o - mu[p]) * rs[p] * gv + bev) * a4[t];
          avp[p * AV_STR + sub * 16 + lc] = f2bf(a);
        }
      }
      __syncthreads();
    }
    // final-conv K-split MFMA: K rows 0..31 = c2 32*pr..+31, fully dense.
    __builtin_amdgcn_sched_barrier(0);
    {
      const unsigned short* bp = avp + (wv * 16 + ln) * AV_STR + quad * 8;
      U128 bfr;
      bfr.u[0] = *(const unsigned long long*)(bp);
      bfr.u[1] = *(const unsigned long long*)(bp + 4);
      #pragma unroll
      for (int mt = 0; mt < 3; ++mt) {
        short8 af = *(const short8*)(w2p + ((pr * 48 + mt * 16 + ln) * 32 + quad * 8));
        oacc[mt] = __builtin_amdgcn_mfma_f32_16x16x32_bf16(af, bfr.s, oacc[mt], 0, 0, 0);
      }
    }
  }

  // ---- store y ----
  #pragma unroll
  for (int mt = 0; mt < 3; ++mt)
    #pragma unroll
    for (int r = 0; r < 4; ++r) {
      int co = mt * 16 + quad * 4 + r;
      y[(((b * C_) + co) * H_ + h) * W_ + w0 + wv * 16 + ln] = oacc[mt][r];
    }
}

extern "C" void kernel_launch(void* const* d_in, const int* in_sizes, int n_in,
                              void* d_out, int out_size, void* d_ws, size_t ws_size,
                              hipStream_t stream) {
  const float* x   = (const float*)d_in[0];
  const float* wh  = (const float*)d_in[1];
  const float* bh  = (const float*)d_in[2];
  const float* wdw = (const float*)d_in[3];
  const float* bdw = (const float*)d_in[4];
  const float* g   = (const float*)d_in[5];
  const float* be  = (const float*)d_in[6];
  const float* wo  = (const float*)d_in[7];
  const float* bo  = (const float*)d_in[8];
  float* y = (float*)d_out;
  unsigned short* ws = (unsigned short*)d_ws;   // 23040 ushorts

  fsas_prep<<<dim3(90), 256, 0, stream>>>(wh, wo, ws);
  dim3 grid(4, H_, B_);
  fsas_fused<<<grid, 256, 0, stream>>>(x, bh, wdw, bdw, g, be, bo, ws, y);
}